// Round 7
// baseline (12662.577 us; speedup 1.0000x reference)
//
#include <hip/hip_runtime.h>
#include <cstdint>
#include <cstddef>

// Problem constants (from reference)
#define NN 50000
#define TT 8
#define FF 128
#define HH 128
#define EE 800000

// binning geometry
#define NBUCK 782   // ceil(NN/64); bucket = dst >> 6
#define NB 128      // blocks per timestep in binning
#define CHUNK 6250  // EE / NB exactly
#define AGG_PAD 132 // padded acc row (floats) to spread banks

typedef __attribute__((ext_vector_type(8))) short bf16x8;
typedef __attribute__((ext_vector_type(4))) float f32x4;
typedef unsigned int uint;
typedef unsigned short ushort;

__device__ __forceinline__ float sigmoidf(float x) { return 1.0f / (1.0f + expf(-x)); }

__device__ __forceinline__ ushort f2bf_rne(float x) {
    uint u = __float_as_uint(x);
    uint r = (u + 0x7FFFu + ((u >> 16) & 1u)) >> 16;
    return (ushort)r;
}
__device__ __forceinline__ float bf2f(ushort b) { return __uint_as_float(((uint)b) << 16); }
__device__ __forceinline__ void split1(float x, ushort& hi, ushort& lo) {
    ushort h = f2bf_rne(x);
    hi = h;
    lo = f2bf_rne(x - bf2f(h));
}

// ---------------- bucket binning (all 8 timesteps) ----------------

// Phase A: per (t, edge-chunk) histogram over 782 buckets via LDS
__global__ __launch_bounds__(256) void bin_hist(const int* __restrict__ ei,
                                                int* __restrict__ histG) {
    __shared__ int hist[NBUCK];
    const int tid = threadIdx.x;
    const int blk = blockIdx.x, t = blockIdx.y;
    for (int i = tid; i < NBUCK; i += 256) hist[i] = 0;
    __syncthreads();
    const int* dst = ei + (size_t)t * 2 * EE + EE;
    const int base = blk * CHUNK;
    for (int i = tid; i < CHUNK; i += 256) atomicAdd(&hist[dst[base + i] >> 6], 1);
    __syncthreads();
    int* hg = histG + (size_t)t * NBUCK * NB;
    for (int i = tid; i < NBUCK; i += 256) hg[i * NB + blk] = hist[i];
}

// Phase B: in-place exclusive scan of histG per t (bucket-major, block-minor);
// also emits per-bucket offsets bOffs[t][buck] (and [NBUCK] = E)
__global__ __launch_bounds__(256) void scan_bins(int* __restrict__ histG,
                                                 int* __restrict__ bOffs) {
    __shared__ int sums[256];
    const int t = blockIdx.x;
    int* hg = histG + (size_t)t * NBUCK * NB;
    int* bo = bOffs + (size_t)t * (NBUCK + 1);
    const int tid = threadIdx.x;
    const int SZ = NBUCK * NB;           // 100096
    const int chunk = (SZ + 255) / 256;  // 391 (391*256 == SZ)
    const int b = tid * chunk, e = min(b + chunk, SZ);
    int s = 0;
    for (int i = b; i < e; ++i) s += hg[i];
    sums[tid] = s;
    __syncthreads();
    for (int o = 1; o < 256; o <<= 1) {
        int v = 0;
        if (tid >= o) v = sums[tid - o];
        __syncthreads();
        if (tid >= o) sums[tid] += v;
        __syncthreads();
    }
    int pre = (tid == 0) ? 0 : sums[tid - 1];
    for (int i = b; i < e; ++i) {
        int v = hg[i];
        hg[i] = pre;
        if ((i & (NB - 1)) == 0) bo[i / NB] = pre;
        pre += v;
    }
    if (tid == 255) bo[NBUCK] = pre;  // == EE
}

// Phase C: scatter packed (dst&63)<<16 | src into bucket-grouped order
__global__ __launch_bounds__(256) void bin_scatter(const int* __restrict__ ei,
                                                   const int* __restrict__ histG,
                                                   uint* __restrict__ binned) {
    __shared__ int cur[NBUCK];
    const int tid = threadIdx.x;
    const int blk = blockIdx.x, t = blockIdx.y;
    const int* hg = histG + (size_t)t * NBUCK * NB;
    for (int i = tid; i < NBUCK; i += 256) cur[i] = hg[i * NB + blk];
    __syncthreads();
    const int* src = ei + (size_t)t * 2 * EE;
    const int* dst = src + EE;
    uint* bn = binned + (size_t)t * EE;
    const int base = blk * CHUNK;
    for (int i = tid; i < CHUNK; i += 256) {
        const int e = base + i;
        const int d = dst[e];
        const int s = src[e];
        const int pos = atomicAdd(&cur[d >> 6], 1);
        bn[pos] = ((uint)(d & 63) << 16) | (uint)s;
    }
}

// degrees + dinv from binned (LDS counters; replaces global-atomic count_all)
__global__ __launch_bounds__(256) void count_bucket(const uint* __restrict__ binned,
                                                    const int* __restrict__ bOffs,
                                                    float* __restrict__ dinv) {
    __shared__ int cnt[64];
    const int tid = threadIdx.x;
    const int buck = blockIdx.x, t = blockIdx.y;
    if (tid < 64) cnt[tid] = 0;
    __syncthreads();
    const int* bo = bOffs + (size_t)t * (NBUCK + 1);
    const uint* bn = binned + (size_t)t * EE;
    const int e0 = bo[buck], e1 = bo[buck + 1];
    for (int e = e0 + tid; e < e1; e += 256) atomicAdd(&cnt[bn[e] >> 16], 1);
    __syncthreads();
    if (tid < 64) {
        const int d = buck * 64 + tid;
        if (d < NN) dinv[(size_t)t * NN + d] = rsqrtf((float)(cnt[tid] + 1));
    }
}

// ---------------- weight prep ----------------
// GCN W [128k][128n] fp32 -> fragment-major bf16 hi/lo
__global__ void prep_w_gcn(const float* __restrict__ W, ushort* __restrict__ oh,
                           ushort* __restrict__ ol) {
    const int bx = blockIdx.x;           // kc5*8 + q, 32 blocks
    const int kc5 = bx >> 3, q = bx & 7;
    const int l = threadIdx.x;           // 64
    const int n = q * 16 + (l & 15);
    const int kb = kc5 * 32 + (l >> 4) * 8;
    const size_t o = ((size_t)bx * 64 + l) * 8;
#pragma unroll
    for (int j = 0; j < 8; ++j) {
        float v = W[(size_t)(kb + j) * 128 + n];
        split1(v, oh[o + j], ol[o + j]);
    }
}

// LSTM W [512 srow][128 k] fp32, gate-permuted cols
__global__ void prep_w_lstm(const float* __restrict__ W, ushort* __restrict__ oh,
                            ushort* __restrict__ ol) {
    const int bx = blockIdx.x;           // kc5*32 + q, 128 blocks
    const int kc5 = bx >> 5, q = bx & 31;
    const int l = threadIdx.x;           // 64
    const int c15 = l & 15;
    const int g = q & 3, kk = q >> 2;
    const int srow = g * 128 + kk * 16 + c15;
    const int kb = kc5 * 32 + (l >> 4) * 8;
    const size_t o = ((size_t)bx * 64 + l) * 8;
#pragma unroll
    for (int j = 0; j < 8; ++j) {
        float v = W[(size_t)srow * 128 + kb + j];
        split1(v, oh[o + j], ol[o + j]);
    }
}

__global__ void prep_bc(const float* __restrict__ bih, const float* __restrict__ bhh,
                        float* __restrict__ bcp) {
    const int cp = threadIdx.x;  // 512
    const int c15 = cp & 15, q = cp >> 4;
    const int g = q & 3, kk = q >> 2;
    const int srow = g * 128 + kk * 16 + c15;
    bcp[cp] = bih[srow] + bhh[srow];
}

// ---------------- GCN GEMM layer 1 (fp32 A via LDS split): hs = (A@W)*dinv ----------------
__global__ __launch_bounds__(256) void gemm_gcn_mfma(const float* __restrict__ A,
                                                     const ushort* __restrict__ Wfh,
                                                     const ushort* __restrict__ Wfl,
                                                     const float* __restrict__ dinv,
                                                     float* __restrict__ C, int M) {
    __shared__ ushort Ah[64][40];
    __shared__ ushort Al[64][40];
    const int tid = threadIdx.x;
    const int lane = tid & 63;
    const int w = tid >> 6;
    const int wm = w >> 1, wn = w & 1;
    const int l15 = lane & 15, l4 = lane >> 4;
    const int m0 = blockIdx.x * 64;

    f32x4 acc[2][4];
#pragma unroll
    for (int i = 0; i < 2; ++i)
#pragma unroll
        for (int j = 0; j < 4; ++j) acc[i][j] = (f32x4){0.f, 0.f, 0.f, 0.f};

    const int srow = tid >> 2;
    const int sseg = tid & 3;
    const bool aval = (m0 + srow) < M;
    const float* aptr = A + (size_t)(m0 + srow) * 128 + sseg * 8;

    for (int kc5 = 0; kc5 < 4; ++kc5) {
        float4 v0 = {0.f, 0.f, 0.f, 0.f}, v1 = {0.f, 0.f, 0.f, 0.f};
        if (aval) {
            v0 = *(const float4*)(aptr + kc5 * 32);
            v1 = *(const float4*)(aptr + kc5 * 32 + 4);
        }
        union { uint4 u; ushort s[8]; } ph, pl;
        split1(v0.x, ph.s[0], pl.s[0]); split1(v0.y, ph.s[1], pl.s[1]);
        split1(v0.z, ph.s[2], pl.s[2]); split1(v0.w, ph.s[3], pl.s[3]);
        split1(v1.x, ph.s[4], pl.s[4]); split1(v1.y, ph.s[5], pl.s[5]);
        split1(v1.z, ph.s[6], pl.s[6]); split1(v1.w, ph.s[7], pl.s[7]);
        *(uint4*)&Ah[srow][sseg * 8] = ph.u;
        *(uint4*)&Al[srow][sseg * 8] = pl.u;
        __syncthreads();

        bf16x8 bh[4], bl[4];
#pragma unroll
        for (int nf = 0; nf < 4; ++nf) {
            const size_t o = ((size_t)(kc5 * 8 + wn * 4 + nf) * 64 + lane) * 8;
            bh[nf] = *(const bf16x8*)(Wfh + o);
            bl[nf] = *(const bf16x8*)(Wfl + o);
        }
        bf16x8 ahf[2], alf[2];
#pragma unroll
        for (int mf = 0; mf < 2; ++mf) {
            ahf[mf] = *(const bf16x8*)&Ah[wm * 32 + mf * 16 + l15][l4 * 8];
            alf[mf] = *(const bf16x8*)&Al[wm * 32 + mf * 16 + l15][l4 * 8];
        }
#pragma unroll
        for (int mf = 0; mf < 2; ++mf)
#pragma unroll
            for (int nf = 0; nf < 4; ++nf) {
                acc[mf][nf] = __builtin_amdgcn_mfma_f32_16x16x32_bf16(ahf[mf], bh[nf], acc[mf][nf], 0, 0, 0);
                acc[mf][nf] = __builtin_amdgcn_mfma_f32_16x16x32_bf16(ahf[mf], bl[nf], acc[mf][nf], 0, 0, 0);
                acc[mf][nf] = __builtin_amdgcn_mfma_f32_16x16x32_bf16(alf[mf], bh[nf], acc[mf][nf], 0, 0, 0);
            }
        __syncthreads();
    }

#pragma unroll
    for (int mf = 0; mf < 2; ++mf)
#pragma unroll
        for (int r = 0; r < 4; ++r) {
            const int row = m0 + wm * 32 + mf * 16 + l4 * 4 + r;
            if (row < M) {
                const float d = dinv[row];
                float* cp = C + (size_t)row * 128 + wn * 64 + l15;
#pragma unroll
                for (int nf = 0; nf < 4; ++nf) cp[nf * 16] = acc[mf][nf][r] * d;
            }
        }
}

// ---------------- GCN GEMM layer 2 (A from bf16 hi/lo planes, no LDS/barriers) ----------------
__global__ __launch_bounds__(256) void gemm_frag(const ushort* __restrict__ Xh,
                                                 const ushort* __restrict__ Xl,
                                                 const ushort* __restrict__ Wfh,
                                                 const ushort* __restrict__ Wfl,
                                                 const float* __restrict__ dinv,
                                                 float* __restrict__ C, int M) {
    const int tid = threadIdx.x;
    const int lane = tid & 63;
    const int w = tid >> 6;
    const int wm = w >> 1, wn = w & 1;
    const int l15 = lane & 15, l4 = lane >> 4;
    const int m0 = blockIdx.x * 64;

    f32x4 acc[2][4];
#pragma unroll
    for (int i = 0; i < 2; ++i)
#pragma unroll
        for (int j = 0; j < 4; ++j) acc[i][j] = (f32x4){0.f, 0.f, 0.f, 0.f};

    size_t abase[2];
#pragma unroll
    for (int mf = 0; mf < 2; ++mf)
        abase[mf] = (size_t)(m0 + wm * 32 + mf * 16 + l15) * 128 + l4 * 8;

#pragma unroll
    for (int kc5 = 0; kc5 < 4; ++kc5) {
        bf16x8 ahf[2], alf[2];
#pragma unroll
        for (int mf = 0; mf < 2; ++mf) {
            ahf[mf] = *(const bf16x8*)(Xh + abase[mf] + kc5 * 32);
            alf[mf] = *(const bf16x8*)(Xl + abase[mf] + kc5 * 32);
        }
#pragma unroll
        for (int nf = 0; nf < 4; ++nf) {
            const size_t o = ((size_t)(kc5 * 8 + wn * 4 + nf) * 64 + lane) * 8;
            const bf16x8 bh = *(const bf16x8*)(Wfh + o);
            const bf16x8 bl = *(const bf16x8*)(Wfl + o);
#pragma unroll
            for (int mf = 0; mf < 2; ++mf) {
                acc[mf][nf] = __builtin_amdgcn_mfma_f32_16x16x32_bf16(ahf[mf], bh, acc[mf][nf], 0, 0, 0);
                acc[mf][nf] = __builtin_amdgcn_mfma_f32_16x16x32_bf16(ahf[mf], bl, acc[mf][nf], 0, 0, 0);
                acc[mf][nf] = __builtin_amdgcn_mfma_f32_16x16x32_bf16(alf[mf], bh, acc[mf][nf], 0, 0, 0);
            }
        }
    }

#pragma unroll
    for (int mf = 0; mf < 2; ++mf)
#pragma unroll
        for (int r = 0; r < 4; ++r) {
            const int row = m0 + wm * 32 + mf * 16 + l4 * 4 + r;
            if (row < M) {
                const float d = dinv[row];
                float* cp = C + (size_t)row * 128 + wn * 64 + l15;
#pragma unroll
                for (int nf = 0; nf < 4; ++nf) cp[nf * 16] = acc[mf][nf][r] * d;
            }
        }
}

// ---------------- bucket aggregate: LDS accumulators, edge-parallel ----------------
// block = one 64-node bucket; 4 waves x 32-feature slices; 8 edges x 8 lanes x float4
__global__ __launch_bounds__(256) void aggregate_bucket(const float* __restrict__ hs,
                                                        const uint* __restrict__ binned,
                                                        const int* __restrict__ bOffs,
                                                        const float* __restrict__ dinv,
                                                        const float* __restrict__ bias,
                                                        ushort* __restrict__ outh,
                                                        ushort* __restrict__ outl, int n) {
    __shared__ float acc[64][AGG_PAD];
    const int tid = threadIdx.x;
    const int buck = blockIdx.x;
    for (int i = tid; i < 64 * AGG_PAD; i += 256) ((float*)acc)[i] = 0.f;
    __syncthreads();

    const int e0 = bOffs[buck], e1 = bOffs[buck + 1];
    const int w = tid >> 6, lane = tid & 63;
    const int eo = lane >> 3, q = lane & 7;
    const int fb = w * 32 + q * 4;
    for (int e = e0; e < e1; e += 8) {
        const int ee = e + eo;
        if (ee < e1) {
            const uint p = binned[ee];
            const int s = p & 0xFFFF;
            const int dl = p >> 16;
            const float4 v = *(const float4*)&hs[(size_t)s * 128 + fb];
            atomicAdd(&acc[dl][fb + 0], v.x);
            atomicAdd(&acc[dl][fb + 1], v.y);
            atomicAdd(&acc[dl][fb + 2], v.z);
            atomicAdd(&acc[dl][fb + 3], v.w);
        }
    }
    __syncthreads();

    // epilogue: 64 nodes x 32 float4 groups = 2048 / 256 threads = 8 each
#pragma unroll
    for (int rep = 0; rep < 8; ++rep) {
        const int idx = rep * 256 + tid;
        const int nd = idx >> 5, fq = idx & 31;
        const int d = buck * 64 + nd;
        if (d >= n) continue;
        const float4 a = *(const float4*)&acc[nd][fq * 4];
        const float4 self = *(const float4*)&hs[(size_t)d * 128 + fq * 4];
        const float4 bb = *(const float4*)&bias[fq * 4];
        const float di = dinv[d];
        const float o0 = fmaxf(di * (a.x + self.x) + bb.x, 0.f);
        const float o1 = fmaxf(di * (a.y + self.y) + bb.y, 0.f);
        const float o2 = fmaxf(di * (a.z + self.z) + bb.z, 0.f);
        const float o3 = fmaxf(di * (a.w + self.w) + bb.w, 0.f);
        ushort h0, l0, h1, l1, h2, l2, h3, l3;
        split1(o0, h0, l0); split1(o1, h1, l1); split1(o2, h2, l2); split1(o3, h3, l3);
        const ushort4 ph = {h0, h1, h2, h3};
        const ushort4 pl = {l0, l1, l2, l3};
        *(ushort4*)&outh[(size_t)d * 128 + fq * 4] = ph;
        *(ushort4*)&outl[(size_t)d * 128 + fq * 4] = pl;
    }
}

// ---------------- fused LSTM step (frag A loads, no LDS, no barriers) ----------------
__global__ __launch_bounds__(512) void lstm_frag(const ushort* __restrict__ Xh,
                                                 const ushort* __restrict__ Xl,
                                                 const ushort* __restrict__ Hinh,
                                                 const ushort* __restrict__ Hinl,
                                                 ushort* __restrict__ Houth,
                                                 ushort* __restrict__ Houtl,
                                                 float* __restrict__ hout,
                                                 float* __restrict__ c,
                                                 const ushort* __restrict__ Wihfh,
                                                 const ushort* __restrict__ Wihfl,
                                                 const ushort* __restrict__ Whhfh,
                                                 const ushort* __restrict__ Whhfl,
                                                 const float* __restrict__ bcp, int M) {
    const int tid = threadIdx.x;
    const int lane = tid & 63;
    const int w = tid >> 6;          // 0..7
    const int wm = w >> 2, wn = w & 3;
    const int l15 = lane & 15, l4 = lane >> 4;
    const int m0 = blockIdx.x * 64;

    f32x4 acc[2][8];
#pragma unroll
    for (int i = 0; i < 2; ++i)
#pragma unroll
        for (int j = 0; j < 8; ++j) acc[i][j] = (f32x4){0.f, 0.f, 0.f, 0.f};

    size_t abase[2];
#pragma unroll
    for (int mf = 0; mf < 2; ++mf)
        abase[mf] = (size_t)(m0 + wm * 32 + mf * 16 + l15) * 128 + l4 * 8;

#pragma unroll
    for (int halfK = 0; halfK < 2; ++halfK) {
        const ushort* Ah = halfK ? Hinh : Xh;
        const ushort* Al = halfK ? Hinl : Xl;
        const ushort* Bfh = halfK ? Whhfh : Wihfh;
        const ushort* Bfl = halfK ? Whhfl : Wihfl;
#pragma unroll
        for (int kc5 = 0; kc5 < 4; ++kc5) {
            bf16x8 ahf[2], alf[2];
#pragma unroll
            for (int mf = 0; mf < 2; ++mf) {
                ahf[mf] = *(const bf16x8*)(Ah + abase[mf] + kc5 * 32);
                alf[mf] = *(const bf16x8*)(Al + abase[mf] + kc5 * 32);
            }
#pragma unroll
            for (int nf = 0; nf < 8; ++nf) {
                const size_t o = ((size_t)(kc5 * 32 + wn * 8 + nf) * 64 + lane) * 8;
                const bf16x8 bh = *(const bf16x8*)(Bfh + o);
                const bf16x8 bl = *(const bf16x8*)(Bfl + o);
#pragma unroll
                for (int mf = 0; mf < 2; ++mf) {
                    acc[mf][nf] = __builtin_amdgcn_mfma_f32_16x16x32_bf16(ahf[mf], bh, acc[mf][nf], 0, 0, 0);
                    acc[mf][nf] = __builtin_amdgcn_mfma_f32_16x16x32_bf16(ahf[mf], bl, acc[mf][nf], 0, 0, 0);
                    acc[mf][nf] = __builtin_amdgcn_mfma_f32_16x16x32_bf16(alf[mf], bh, acc[mf][nf], 0, 0, 0);
                }
            }
        }
    }

    float bb[8];
#pragma unroll
    for (int nf = 0; nf < 8; ++nf) bb[nf] = bcp[l15 + 16 * (wn * 8 + nf)];
#pragma unroll
    for (int mf = 0; mf < 2; ++mf)
#pragma unroll
        for (int r = 0; r < 4; ++r) {
            const int row = m0 + wm * 32 + mf * 16 + l4 * 4 + r;
            if (row >= M) continue;
#pragma unroll
            for (int kl = 0; kl < 2; ++kl) {
                const float gi = acc[mf][kl * 4 + 0][r] + bb[kl * 4 + 0];
                const float gf = acc[mf][kl * 4 + 1][r] + bb[kl * 4 + 1];
                const float gg = acc[mf][kl * 4 + 2][r] + bb[kl * 4 + 2];
                const float go = acc[mf][kl * 4 + 3][r] + bb[kl * 4 + 3];
                const int k = (2 * wn + kl) * 16 + l15;
                const size_t idx = (size_t)row * 128 + k;
                const float cn = sigmoidf(gf) * c[idx] + sigmoidf(gi) * tanhf(gg);
                const float hn = sigmoidf(go) * tanhf(cn);
                c[idx] = cn;
                hout[idx] = hn;
                ushort hh, hl;
                split1(hn, hh, hl);
                Houth[idx] = hh;
                Houtl[idx] = hl;
            }
        }
}

// ---------------- launch ----------------
extern "C" void kernel_launch(void* const* d_in, const int* in_sizes, int n_in,
                              void* d_out, int out_size, void* d_ws, size_t ws_size,
                              hipStream_t stream) {
    const float* nf  = (const float*)d_in[0];  // [T,N,F]
    const int*   ei  = (const int*)d_in[1];    // [T,2,E]
    const float* W1  = (const float*)d_in[2];
    const float* b1  = (const float*)d_in[3];
    const float* W2  = (const float*)d_in[4];
    const float* b2  = (const float*)d_in[5];
    const float* Wih = (const float*)d_in[6];  // [512,128]
    const float* Whh = (const float*)d_in[7];
    const float* bih = (const float*)d_in[8];
    const float* bhh = (const float*)d_in[9];
    float* h = (float*)d_out;  // [N,128] fp32 hidden (final answer)

    const size_t AL = 256;
    auto rnd = [&](size_t b) { return (b + AL - 1) & ~(AL - 1); };
    const size_t sz_feat  = (size_t)NN * 128 * 4;   // fp32 plane
    const size_t sz_plane = (size_t)NN * 128 * 2;   // bf16 plane
    const size_t need = rnd(sz_feat) * 2                       // hs, c
                      + rnd(sz_plane) * 6                      // xh,xl + h ping-pong hi/lo
                      + rnd((size_t)TT * EE * 4)               // binned
                      + rnd((size_t)TT * NBUCK * NB * 4)       // histG
                      + rnd((size_t)TT * (NBUCK + 1) * 4)      // bOffs
                      + rnd((size_t)TT * NN * 4)               // dinv
                      + rnd((size_t)128 * 128 * 2) * 4
                      + rnd((size_t)512 * 128 * 2) * 4
                      + rnd(512 * 4);
    if (ws_size < need) return;  // fail visibly (incorrect), not fatally

    char* ws = (char*)d_ws;
    size_t off = 0;
    auto alloc = [&](size_t bytes) -> void* {
        void* p = ws + off;
        off += rnd(bytes);
        return p;
    };
    float*  hs     = (float*)alloc(sz_feat);
    float*  c      = (float*)alloc(sz_feat);
    ushort* xh     = (ushort*)alloc(sz_plane);
    ushort* xl     = (ushort*)alloc(sz_plane);
    ushort* hp0h   = (ushort*)alloc(sz_plane);
    ushort* hp0l   = (ushort*)alloc(sz_plane);
    ushort* hp1h   = (ushort*)alloc(sz_plane);
    ushort* hp1l   = (ushort*)alloc(sz_plane);
    uint*   binned = (uint*)alloc((size_t)TT * EE * 4);
    int*    histG  = (int*)alloc((size_t)TT * NBUCK * NB * 4);
    int*    bOffs  = (int*)alloc((size_t)TT * (NBUCK + 1) * 4);
    float*  dinv   = (float*)alloc((size_t)TT * NN * 4);
    ushort* wf1h   = (ushort*)alloc((size_t)128 * 128 * 2);
    ushort* wf1l   = (ushort*)alloc((size_t)128 * 128 * 2);
    ushort* wf2h   = (ushort*)alloc((size_t)128 * 128 * 2);
    ushort* wf2l   = (ushort*)alloc((size_t)128 * 128 * 2);
    ushort* wihfh  = (ushort*)alloc((size_t)512 * 128 * 2);
    ushort* wihfl  = (ushort*)alloc((size_t)512 * 128 * 2);
    ushort* whhfh  = (ushort*)alloc((size_t)512 * 128 * 2);
    ushort* whhfl  = (ushort*)alloc((size_t)512 * 128 * 2);
    float*  bcp    = (float*)alloc(512 * 4);

    // init
    hipMemsetAsync(c, 0, sz_feat, stream);
    hipMemsetAsync(hp0h, 0, sz_plane, stream);  // bf16 +0.0 == 0x0000
    hipMemsetAsync(hp0l, 0, sz_plane, stream);

    // bucket binning for all 8 timesteps
    bin_hist<<<dim3(NB, TT), 256, 0, stream>>>(ei, histG);
    scan_bins<<<TT, 256, 0, stream>>>(histG, bOffs);
    bin_scatter<<<dim3(NB, TT), 256, 0, stream>>>(ei, histG, binned);
    count_bucket<<<dim3(NBUCK, TT), 256, 0, stream>>>(binned, bOffs, dinv);

    // weight prep
    prep_w_gcn<<<32, 64, 0, stream>>>(W1, wf1h, wf1l);
    prep_w_gcn<<<32, 64, 0, stream>>>(W2, wf2h, wf2l);
    prep_w_lstm<<<128, 64, 0, stream>>>(Wih, wihfh, wihfl);
    prep_w_lstm<<<128, 64, 0, stream>>>(Whh, whhfh, whhfl);
    prep_bc<<<1, 512, 0, stream>>>(bih, bhh, bcp);

    const int gm64 = (NN + 63) / 64;  // 782

    for (int t = 0; t < TT; ++t) {
        const float* x = nf + (size_t)t * NN * FF;
        const float* dv = dinv + (size_t)t * NN;
        const uint* bn = binned + (size_t)t * EE;
        const int* bo = bOffs + (size_t)t * (NBUCK + 1);

        // GCN layer 1 (fp32 A, LDS split)
        gemm_gcn_mfma<<<gm64, 256, 0, stream>>>(x, wf1h, wf1l, dv, hs, NN);
        aggregate_bucket<<<NBUCK, 256, 0, stream>>>(hs, bn, bo, dv, b1, xh, xl, NN);
        // GCN layer 2 (bf16 planes A, no LDS)
        gemm_frag<<<gm64, 256, 0, stream>>>(xh, xl, wf2h, wf2l, dv, hs, NN);
        aggregate_bucket<<<NBUCK, 256, 0, stream>>>(hs, bn, bo, dv, b2, xh, xl, NN);

        // fused LSTM step (h planes ping-pong)
        const ushort* hinh = (t & 1) ? hp1h : hp0h;
        const ushort* hinl = (t & 1) ? hp1l : hp0l;
        ushort* houth = (t & 1) ? hp0h : hp1h;
        ushort* houtl = (t & 1) ? hp0l : hp1l;
        lstm_frag<<<gm64, 512, 0, stream>>>(xh, xl, hinh, hinl, houth, houtl, h, c,
                                            wihfh, wihfl, whhfh, whhfl, bcp, NN);
    }
}

// Round 9
// 2710.405 us; speedup vs baseline: 4.6718x; 4.6718x over previous
//
#include <hip/hip_runtime.h>
#include <cstdint>
#include <cstddef>

// Problem constants (from reference)
#define NN 50000
#define TT 8
#define FF 128
#define HH 128
#define EE 800000

// binning geometry
#define NBUCK 782   // ceil(NN/64); bucket = dst >> 6
#define NB 128      // blocks per timestep in binning
#define CHUNK 6250  // EE / NB exactly

typedef __attribute__((ext_vector_type(8))) short bf16x8;
typedef __attribute__((ext_vector_type(4))) float f32x4;
typedef unsigned int uint;
typedef unsigned short ushort;

__device__ __forceinline__ float sigmoidf(float x) { return 1.0f / (1.0f + expf(-x)); }

__device__ __forceinline__ ushort f2bf_rne(float x) {
    uint u = __float_as_uint(x);
    uint r = (u + 0x7FFFu + ((u >> 16) & 1u)) >> 16;
    return (ushort)r;
}
__device__ __forceinline__ float bf2f(ushort b) { return __uint_as_float(((uint)b) << 16); }
__device__ __forceinline__ void split1(float x, ushort& hi, ushort& lo) {
    ushort h = f2bf_rne(x);
    hi = h;
    lo = f2bf_rne(x - bf2f(h));
}

// ---------------- bucket binning (all 8 timesteps) ----------------

// Phase A: per (t, edge-chunk) histogram over 782 buckets via LDS
__global__ __launch_bounds__(256) void bin_hist(const int* __restrict__ ei,
                                                int* __restrict__ histG) {
    __shared__ int hist[NBUCK];
    const int tid = threadIdx.x;
    const int blk = blockIdx.x, t = blockIdx.y;
    for (int i = tid; i < NBUCK; i += 256) hist[i] = 0;
    __syncthreads();
    const int* dst = ei + (size_t)t * 2 * EE + EE;
    const int base = blk * CHUNK;
    for (int i = tid; i < CHUNK; i += 256) atomicAdd(&hist[dst[base + i] >> 6], 1);
    __syncthreads();
    int* hg = histG + (size_t)t * NBUCK * NB;
    for (int i = tid; i < NBUCK; i += 256) hg[i * NB + blk] = hist[i];
}

// Phase B: in-place exclusive scan of histG per t; emits per-bucket offsets
__global__ __launch_bounds__(256) void scan_bins(int* __restrict__ histG,
                                                 int* __restrict__ bOffs) {
    __shared__ int sums[256];
    const int t = blockIdx.x;
    int* hg = histG + (size_t)t * NBUCK * NB;
    int* bo = bOffs + (size_t)t * (NBUCK + 1);
    const int tid = threadIdx.x;
    const int SZ = NBUCK * NB;           // 100096
    const int chunk = (SZ + 255) / 256;  // 391
    const int b = tid * chunk, e = min(b + chunk, SZ);
    int s = 0;
    for (int i = b; i < e; ++i) s += hg[i];
    sums[tid] = s;
    __syncthreads();
    for (int o = 1; o < 256; o <<= 1) {
        int v = 0;
        if (tid >= o) v = sums[tid - o];
        __syncthreads();
        if (tid >= o) sums[tid] += v;
        __syncthreads();
    }
    int pre = (tid == 0) ? 0 : sums[tid - 1];
    for (int i = b; i < e; ++i) {
        int v = hg[i];
        hg[i] = pre;
        if ((i & (NB - 1)) == 0) bo[i / NB] = pre;
        pre += v;
    }
    if (tid == 255) bo[NBUCK] = pre;  // == EE
}

// Phase C: scatter packed (dst&63)<<16 | src into bucket-grouped order
__global__ __launch_bounds__(256) void bin_scatter(const int* __restrict__ ei,
                                                   const int* __restrict__ histG,
                                                   uint* __restrict__ binned) {
    __shared__ int cur[NBUCK];
    const int tid = threadIdx.x;
    const int blk = blockIdx.x, t = blockIdx.y;
    const int* hg = histG + (size_t)t * NBUCK * NB;
    for (int i = tid; i < NBUCK; i += 256) cur[i] = hg[i * NB + blk];
    __syncthreads();
    const int* src = ei + (size_t)t * 2 * EE;
    const int* dst = src + EE;
    uint* bn = binned + (size_t)t * EE;
    const int base = blk * CHUNK;
    for (int i = tid; i < CHUNK; i += 256) {
        const int e = base + i;
        const int d = dst[e];
        const int s = src[e];
        const int pos = atomicAdd(&cur[d >> 6], 1);
        bn[pos] = ((uint)(d & 63) << 16) | (uint)s;
    }
}

// Phase D: bucket-grouped -> exact per-node CSR (offs, sorted, dinv)
// one block per (bucket, t); all writes land in this bucket's contiguous window
__global__ __launch_bounds__(256) void bucket_csr(const uint* __restrict__ binned,
                                                  const int* __restrict__ bOffs,
                                                  int* __restrict__ sorted,
                                                  int* __restrict__ offs,
                                                  float* __restrict__ dinv) {
    __shared__ int cnt[64];
    __shared__ int base[64];
    const int tid = threadIdx.x;
    const int buck = blockIdx.x, t = blockIdx.y;
    if (tid < 64) cnt[tid] = 0;
    __syncthreads();
    const int* bo = bOffs + (size_t)t * (NBUCK + 1);
    const uint* bn = binned + (size_t)t * EE;
    const int e0 = bo[buck], e1 = bo[buck + 1];
    for (int e = e0 + tid; e < e1; e += 256) atomicAdd(&cnt[bn[e] >> 16], 1);
    __syncthreads();
    if (tid == 0) {
        int pre = e0;
#pragma unroll
        for (int i = 0; i < 64; ++i) { base[i] = pre; pre += cnt[i]; }
    }
    __syncthreads();
    if (tid < 64) {
        const int d = buck * 64 + tid;
        if (d < NN) {
            offs[(size_t)t * (NN + 1) + d] = base[tid];
            dinv[(size_t)t * NN + d] = rsqrtf((float)(cnt[tid] + 1));
        }
        cnt[tid] = 0;  // reuse as cursor
    }
    __syncthreads();
    int* so = sorted + (size_t)t * EE;
    for (int e = e0 + tid; e < e1; e += 256) {
        const uint p = bn[e];
        const int dl = p >> 16;
        const int pos = base[dl] + atomicAdd(&cnt[dl], 1);
        so[pos] = (int)(p & 0xFFFF);
    }
    if (buck == 0 && tid == 0) offs[(size_t)t * (NN + 1) + NN] = EE;
}

// ---------------- weight prep ----------------
__global__ void prep_w_gcn(const float* __restrict__ W, ushort* __restrict__ oh,
                           ushort* __restrict__ ol) {
    const int bx = blockIdx.x;           // kc5*8 + q, 32 blocks
    const int kc5 = bx >> 3, q = bx & 7;
    const int l = threadIdx.x;           // 64
    const int n = q * 16 + (l & 15);
    const int kb = kc5 * 32 + (l >> 4) * 8;
    const size_t o = ((size_t)bx * 64 + l) * 8;
#pragma unroll
    for (int j = 0; j < 8; ++j) {
        float v = W[(size_t)(kb + j) * 128 + n];
        split1(v, oh[o + j], ol[o + j]);
    }
}

__global__ void prep_w_lstm(const float* __restrict__ W, ushort* __restrict__ oh,
                            ushort* __restrict__ ol) {
    const int bx = blockIdx.x;           // kc5*32 + q, 128 blocks
    const int kc5 = bx >> 5, q = bx & 31;
    const int l = threadIdx.x;           // 64
    const int c15 = l & 15;
    const int g = q & 3, kk = q >> 2;
    const int srow = g * 128 + kk * 16 + c15;
    const int kb = kc5 * 32 + (l >> 4) * 8;
    const size_t o = ((size_t)bx * 64 + l) * 8;
#pragma unroll
    for (int j = 0; j < 8; ++j) {
        float v = W[(size_t)srow * 128 + kb + j];
        split1(v, oh[o + j], ol[o + j]);
    }
}

__global__ void prep_bc(const float* __restrict__ bih, const float* __restrict__ bhh,
                        float* __restrict__ bcp) {
    const int cp = threadIdx.x;  // 512
    const int c15 = cp & 15, q = cp >> 4;
    const int g = q & 3, kk = q >> 2;
    const int srow = g * 128 + kk * 16 + c15;
    bcp[cp] = bih[srow] + bhh[srow];
}

// ---------------- GCN GEMM layer 1 (fp32 A via LDS split): hs = (A@W)*dinv ----------------
__global__ __launch_bounds__(256) void gemm_gcn_mfma(const float* __restrict__ A,
                                                     const ushort* __restrict__ Wfh,
                                                     const ushort* __restrict__ Wfl,
                                                     const float* __restrict__ dinv,
                                                     float* __restrict__ C, int M) {
    __shared__ ushort Ah[64][40];
    __shared__ ushort Al[64][40];
    const int tid = threadIdx.x;
    const int lane = tid & 63;
    const int w = tid >> 6;
    const int wm = w >> 1, wn = w & 1;
    const int l15 = lane & 15, l4 = lane >> 4;
    const int m0 = blockIdx.x * 64;

    f32x4 acc[2][4];
#pragma unroll
    for (int i = 0; i < 2; ++i)
#pragma unroll
        for (int j = 0; j < 4; ++j) acc[i][j] = (f32x4){0.f, 0.f, 0.f, 0.f};

    const int srow = tid >> 2;
    const int sseg = tid & 3;
    const bool aval = (m0 + srow) < M;
    const float* aptr = A + (size_t)(m0 + srow) * 128 + sseg * 8;

    for (int kc5 = 0; kc5 < 4; ++kc5) {
        float4 v0 = {0.f, 0.f, 0.f, 0.f}, v1 = {0.f, 0.f, 0.f, 0.f};
        if (aval) {
            v0 = *(const float4*)(aptr + kc5 * 32);
            v1 = *(const float4*)(aptr + kc5 * 32 + 4);
        }
        union { uint4 u; ushort s[8]; } ph, pl;
        split1(v0.x, ph.s[0], pl.s[0]); split1(v0.y, ph.s[1], pl.s[1]);
        split1(v0.z, ph.s[2], pl.s[2]); split1(v0.w, ph.s[3], pl.s[3]);
        split1(v1.x, ph.s[4], pl.s[4]); split1(v1.y, ph.s[5], pl.s[5]);
        split1(v1.z, ph.s[6], pl.s[6]); split1(v1.w, ph.s[7], pl.s[7]);
        *(uint4*)&Ah[srow][sseg * 8] = ph.u;
        *(uint4*)&Al[srow][sseg * 8] = pl.u;
        __syncthreads();

        bf16x8 bh[4], bl[4];
#pragma unroll
        for (int nf = 0; nf < 4; ++nf) {
            const size_t o = ((size_t)(kc5 * 8 + wn * 4 + nf) * 64 + lane) * 8;
            bh[nf] = *(const bf16x8*)(Wfh + o);
            bl[nf] = *(const bf16x8*)(Wfl + o);
        }
        bf16x8 ahf[2], alf[2];
#pragma unroll
        for (int mf = 0; mf < 2; ++mf) {
            ahf[mf] = *(const bf16x8*)&Ah[wm * 32 + mf * 16 + l15][l4 * 8];
            alf[mf] = *(const bf16x8*)&Al[wm * 32 + mf * 16 + l15][l4 * 8];
        }
#pragma unroll
        for (int mf = 0; mf < 2; ++mf)
#pragma unroll
            for (int nf = 0; nf < 4; ++nf) {
                acc[mf][nf] = __builtin_amdgcn_mfma_f32_16x16x32_bf16(ahf[mf], bh[nf], acc[mf][nf], 0, 0, 0);
                acc[mf][nf] = __builtin_amdgcn_mfma_f32_16x16x32_bf16(ahf[mf], bl[nf], acc[mf][nf], 0, 0, 0);
                acc[mf][nf] = __builtin_amdgcn_mfma_f32_16x16x32_bf16(alf[mf], bh[nf], acc[mf][nf], 0, 0, 0);
            }
        __syncthreads();
    }

#pragma unroll
    for (int mf = 0; mf < 2; ++mf)
#pragma unroll
        for (int r = 0; r < 4; ++r) {
            const int row = m0 + wm * 32 + mf * 16 + l4 * 4 + r;
            if (row < M) {
                const float d = dinv[row];
                float* cp = C + (size_t)row * 128 + wn * 64 + l15;
#pragma unroll
                for (int nf = 0; nf < 4; ++nf) cp[nf * 16] = acc[mf][nf][r] * d;
            }
        }
}

// ---------------- GCN GEMM layer 2 (A from bf16 hi/lo planes, no LDS/barriers) ----------------
__global__ __launch_bounds__(256) void gemm_frag(const ushort* __restrict__ Xh,
                                                 const ushort* __restrict__ Xl,
                                                 const ushort* __restrict__ Wfh,
                                                 const ushort* __restrict__ Wfl,
                                                 const float* __restrict__ dinv,
                                                 float* __restrict__ C, int M) {
    const int tid = threadIdx.x;
    const int lane = tid & 63;
    const int w = tid >> 6;
    const int wm = w >> 1, wn = w & 1;
    const int l15 = lane & 15, l4 = lane >> 4;
    const int m0 = blockIdx.x * 64;

    f32x4 acc[2][4];
#pragma unroll
    for (int i = 0; i < 2; ++i)
#pragma unroll
        for (int j = 0; j < 4; ++j) acc[i][j] = (f32x4){0.f, 0.f, 0.f, 0.f};

    size_t abase[2];
#pragma unroll
    for (int mf = 0; mf < 2; ++mf)
        abase[mf] = (size_t)(m0 + wm * 32 + mf * 16 + l15) * 128 + l4 * 8;

#pragma unroll
    for (int kc5 = 0; kc5 < 4; ++kc5) {
        bf16x8 ahf[2], alf[2];
#pragma unroll
        for (int mf = 0; mf < 2; ++mf) {
            ahf[mf] = *(const bf16x8*)(Xh + abase[mf] + kc5 * 32);
            alf[mf] = *(const bf16x8*)(Xl + abase[mf] + kc5 * 32);
        }
#pragma unroll
        for (int nf = 0; nf < 4; ++nf) {
            const size_t o = ((size_t)(kc5 * 8 + wn * 4 + nf) * 64 + lane) * 8;
            const bf16x8 bh = *(const bf16x8*)(Wfh + o);
            const bf16x8 bl = *(const bf16x8*)(Wfl + o);
#pragma unroll
            for (int mf = 0; mf < 2; ++mf) {
                acc[mf][nf] = __builtin_amdgcn_mfma_f32_16x16x32_bf16(ahf[mf], bh, acc[mf][nf], 0, 0, 0);
                acc[mf][nf] = __builtin_amdgcn_mfma_f32_16x16x32_bf16(ahf[mf], bl, acc[mf][nf], 0, 0, 0);
                acc[mf][nf] = __builtin_amdgcn_mfma_f32_16x16x32_bf16(alf[mf], bh, acc[mf][nf], 0, 0, 0);
            }
        }
    }

#pragma unroll
    for (int mf = 0; mf < 2; ++mf)
#pragma unroll
        for (int r = 0; r < 4; ++r) {
            const int row = m0 + wm * 32 + mf * 16 + l4 * 4 + r;
            if (row < M) {
                const float d = dinv[row];
                float* cp = C + (size_t)row * 128 + wn * 64 + l15;
#pragma unroll
                for (int nf = 0; nf < 4; ++nf) cp[nf * 16] = acc[mf][nf][r] * d;
            }
        }
}

// ---------------- aggregate: wave per node, quarter-wave per edge, 8 edges in flight ----------------
__global__ __launch_bounds__(256) void aggregate_q(const float* __restrict__ hs,
                                                   const int* __restrict__ offs,
                                                   const int* __restrict__ sorted,
                                                   const float* __restrict__ dinv,
                                                   const float* __restrict__ bias,
                                                   ushort* __restrict__ outh,
                                                   ushort* __restrict__ outl, int n) {
    const int lane = threadIdx.x & 63;
    const int qt = lane >> 4, li = lane & 15;
    const int wave = (blockIdx.x * blockDim.x + threadIdx.x) >> 6;
    const int nwaves = (gridDim.x * blockDim.x) >> 6;
    for (int d = wave; d < n; d += nwaves) {
        const int e0 = offs[d], e1 = offs[d + 1];
        float4 a0 = {0, 0, 0, 0}, b0 = {0, 0, 0, 0};
        float4 a1 = {0, 0, 0, 0}, b1 = {0, 0, 0, 0};
        const int fb = li * 8;
        for (int e = e0; e < e1; e += 8) {
            const int sl = ((lane < 8) && (e + lane < e1)) ? sorted[e + lane] : 0;
            const int s0 = __shfl(sl, qt);
            const int s1 = __shfl(sl, qt + 4);
            if (e + qt < e1) {
                const float4 v0 = *(const float4*)&hs[(size_t)s0 * 128 + fb];
                const float4 v1 = *(const float4*)&hs[(size_t)s0 * 128 + fb + 4];
                a0.x += v0.x; a0.y += v0.y; a0.z += v0.z; a0.w += v0.w;
                b0.x += v1.x; b0.y += v1.y; b0.z += v1.z; b0.w += v1.w;
            }
            if (e + qt + 4 < e1) {
                const float4 v0 = *(const float4*)&hs[(size_t)s1 * 128 + fb];
                const float4 v1 = *(const float4*)&hs[(size_t)s1 * 128 + fb + 4];
                a1.x += v0.x; a1.y += v0.y; a1.z += v0.z; a1.w += v0.w;
                b1.x += v1.x; b1.y += v1.y; b1.z += v1.z; b1.w += v1.w;
            }
        }
        a0.x += a1.x; a0.y += a1.y; a0.z += a1.z; a0.w += a1.w;
        b0.x += b1.x; b0.y += b1.y; b0.z += b1.z; b0.w += b1.w;
        // cross-quarter reduce (lanes differing in bits 4,5)
#pragma unroll
        for (int m = 16; m <= 32; m <<= 1) {
            a0.x += __shfl_xor(a0.x, m); a0.y += __shfl_xor(a0.y, m);
            a0.z += __shfl_xor(a0.z, m); a0.w += __shfl_xor(a0.w, m);
            b0.x += __shfl_xor(b0.x, m); b0.y += __shfl_xor(b0.y, m);
            b0.z += __shfl_xor(b0.z, m); b0.w += __shfl_xor(b0.w, m);
        }

        const float di = dinv[d];
        const float4 s0 = *(const float4*)&hs[(size_t)d * 128 + fb];
        const float4 s1 = *(const float4*)&hs[(size_t)d * 128 + fb + 4];
        const float4 c0 = *(const float4*)&bias[fb];
        const float4 c1 = *(const float4*)&bias[fb + 4];
        float o[8];
        o[0] = fmaxf(di * (a0.x + s0.x) + c0.x, 0.f);
        o[1] = fmaxf(di * (a0.y + s0.y) + c0.y, 0.f);
        o[2] = fmaxf(di * (a0.z + s0.z) + c0.z, 0.f);
        o[3] = fmaxf(di * (a0.w + s0.w) + c0.w, 0.f);
        o[4] = fmaxf(di * (b0.x + s1.x) + c1.x, 0.f);
        o[5] = fmaxf(di * (b0.y + s1.y) + c1.y, 0.f);
        o[6] = fmaxf(di * (b0.z + s1.z) + c1.z, 0.f);
        o[7] = fmaxf(di * (b0.w + s1.w) + c1.w, 0.f);
        ushort hh[8], ll[8];
#pragma unroll
        for (int j = 0; j < 8; ++j) split1(o[j], hh[j], ll[j]);
        if (qt == 0) {
            ushort4 p0 = {hh[0], hh[1], hh[2], hh[3]};
            ushort4 p1 = {hh[4], hh[5], hh[6], hh[7]};
            *(ushort4*)&outh[(size_t)d * 128 + fb] = p0;
            *(ushort4*)&outh[(size_t)d * 128 + fb + 4] = p1;
        } else if (qt == 1) {
            ushort4 p0 = {ll[0], ll[1], ll[2], ll[3]};
            ushort4 p1 = {ll[4], ll[5], ll[6], ll[7]};
            *(ushort4*)&outl[(size_t)d * 128 + fb] = p0;
            *(ushort4*)&outl[(size_t)d * 128 + fb + 4] = p1;
        }
    }
}

// ---------------- fused LSTM step (frag A loads, no LDS, no barriers) ----------------
__global__ __launch_bounds__(512) void lstm_frag(const ushort* __restrict__ Xh,
                                                 const ushort* __restrict__ Xl,
                                                 const ushort* __restrict__ Hinh,
                                                 const ushort* __restrict__ Hinl,
                                                 ushort* __restrict__ Houth,
                                                 ushort* __restrict__ Houtl,
                                                 float* __restrict__ hout,
                                                 float* __restrict__ c,
                                                 const ushort* __restrict__ Wihfh,
                                                 const ushort* __restrict__ Wihfl,
                                                 const ushort* __restrict__ Whhfh,
                                                 const ushort* __restrict__ Whhfl,
                                                 const float* __restrict__ bcp, int M) {
    const int tid = threadIdx.x;
    const int lane = tid & 63;
    const int w = tid >> 6;          // 0..7
    const int wm = w >> 2, wn = w & 3;
    const int l15 = lane & 15, l4 = lane >> 4;
    const int m0 = blockIdx.x * 64;

    f32x4 acc[2][8];
#pragma unroll
    for (int i = 0; i < 2; ++i)
#pragma unroll
        for (int j = 0; j < 8; ++j) acc[i][j] = (f32x4){0.f, 0.f, 0.f, 0.f};

    size_t abase[2];
#pragma unroll
    for (int mf = 0; mf < 2; ++mf)
        abase[mf] = (size_t)(m0 + wm * 32 + mf * 16 + l15) * 128 + l4 * 8;

#pragma unroll
    for (int halfK = 0; halfK < 2; ++halfK) {
        const ushort* Ah = halfK ? Hinh : Xh;
        const ushort* Al = halfK ? Hinl : Xl;
        const ushort* Bfh = halfK ? Whhfh : Wihfh;
        const ushort* Bfl = halfK ? Whhfl : Wihfl;
#pragma unroll
        for (int kc5 = 0; kc5 < 4; ++kc5) {
            bf16x8 ahf[2], alf[2];
#pragma unroll
            for (int mf = 0; mf < 2; ++mf) {
                ahf[mf] = *(const bf16x8*)(Ah + abase[mf] + kc5 * 32);
                alf[mf] = *(const bf16x8*)(Al + abase[mf] + kc5 * 32);
            }
#pragma unroll
            for (int nf = 0; nf < 8; ++nf) {
                const size_t o = ((size_t)(kc5 * 32 + wn * 8 + nf) * 64 + lane) * 8;
                const bf16x8 bh = *(const bf16x8*)(Bfh + o);
                const bf16x8 bl = *(const bf16x8*)(Bfl + o);
#pragma unroll
                for (int mf = 0; mf < 2; ++mf) {
                    acc[mf][nf] = __builtin_amdgcn_mfma_f32_16x16x32_bf16(ahf[mf], bh, acc[mf][nf], 0, 0, 0);
                    acc[mf][nf] = __builtin_amdgcn_mfma_f32_16x16x32_bf16(ahf[mf], bl, acc[mf][nf], 0, 0, 0);
                    acc[mf][nf] = __builtin_amdgcn_mfma_f32_16x16x32_bf16(alf[mf], bh, acc[mf][nf], 0, 0, 0);
                }
            }
        }
    }

    float bb[8];
#pragma unroll
    for (int nf = 0; nf < 8; ++nf) bb[nf] = bcp[l15 + 16 * (wn * 8 + nf)];
#pragma unroll
    for (int mf = 0; mf < 2; ++mf)
#pragma unroll
        for (int r = 0; r < 4; ++r) {
            const int row = m0 + wm * 32 + mf * 16 + l4 * 4 + r;
            if (row >= M) continue;
#pragma unroll
            for (int kl = 0; kl < 2; ++kl) {
                const float gi = acc[mf][kl * 4 + 0][r] + bb[kl * 4 + 0];
                const float gf = acc[mf][kl * 4 + 1][r] + bb[kl * 4 + 1];
                const float gg = acc[mf][kl * 4 + 2][r] + bb[kl * 4 + 2];
                const float go = acc[mf][kl * 4 + 3][r] + bb[kl * 4 + 3];
                const int k = (2 * wn + kl) * 16 + l15;
                const size_t idx = (size_t)row * 128 + k;
                const float cn = sigmoidf(gf) * c[idx] + sigmoidf(gi) * tanhf(gg);
                const float hn = sigmoidf(go) * tanhf(cn);
                c[idx] = cn;
                hout[idx] = hn;
                ushort hh, hl;
                split1(hn, hh, hl);
                Houth[idx] = hh;
                Houtl[idx] = hl;
            }
        }
}

// ---------------- launch ----------------
extern "C" void kernel_launch(void* const* d_in, const int* in_sizes, int n_in,
                              void* d_out, int out_size, void* d_ws, size_t ws_size,
                              hipStream_t stream) {
    const float* nf  = (const float*)d_in[0];  // [T,N,F]
    const int*   ei  = (const int*)d_in[1];    // [T,2,E]
    const float* W1  = (const float*)d_in[2];
    const float* b1  = (const float*)d_in[3];
    const float* W2  = (const float*)d_in[4];
    const float* b2  = (const float*)d_in[5];
    const float* Wih = (const float*)d_in[6];  // [512,128]
    const float* Whh = (const float*)d_in[7];
    const float* bih = (const float*)d_in[8];
    const float* bhh = (const float*)d_in[9];
    float* h = (float*)d_out;  // [N,128] fp32 hidden (final answer)

    const size_t AL = 256;
    auto rnd = [&](size_t b) { return (b + AL - 1) & ~(AL - 1); };
    const size_t sz_feat  = (size_t)NN * 128 * 4;   // fp32 plane
    const size_t sz_plane = (size_t)NN * 128 * 2;   // bf16 plane
    const size_t need = rnd(sz_feat) * 2                       // hs, c
                      + rnd(sz_plane) * 6                      // xh,xl + h ping-pong hi/lo
                      + rnd((size_t)TT * EE * 4) * 2           // binned, sorted
                      + rnd((size_t)TT * NBUCK * NB * 4)       // histG
                      + rnd((size_t)TT * (NBUCK + 1) * 4)      // bOffs
                      + rnd((size_t)TT * (NN + 1) * 4)         // offs
                      + rnd((size_t)TT * NN * 4)               // dinv
                      + rnd((size_t)128 * 128 * 2) * 4
                      + rnd((size_t)512 * 128 * 2) * 4
                      + rnd(512 * 4);
    if (ws_size < need) return;  // fail visibly (incorrect), not fatally

    char* ws = (char*)d_ws;
    size_t off = 0;
    auto alloc = [&](size_t bytes) -> void* {
        void* p = ws + off;
        off += rnd(bytes);
        return p;
    };
    float*  hs     = (float*)alloc(sz_feat);
    float*  c      = (float*)alloc(sz_feat);
    ushort* xh     = (ushort*)alloc(sz_plane);
    ushort* xl     = (ushort*)alloc(sz_plane);
    ushort* hp0h   = (ushort*)alloc(sz_plane);
    ushort* hp0l   = (ushort*)alloc(sz_plane);
    ushort* hp1h   = (ushort*)alloc(sz_plane);
    ushort* hp1l   = (ushort*)alloc(sz_plane);
    uint*   binned = (uint*)alloc((size_t)TT * EE * 4);
    int*    sorted = (int*)alloc((size_t)TT * EE * 4);
    int*    histG  = (int*)alloc((size_t)TT * NBUCK * NB * 4);
    int*    bOffs  = (int*)alloc((size_t)TT * (NBUCK + 1) * 4);
    int*    offs   = (int*)alloc((size_t)TT * (NN + 1) * 4);
    float*  dinv   = (float*)alloc((size_t)TT * NN * 4);
    ushort* wf1h   = (ushort*)alloc((size_t)128 * 128 * 2);
    ushort* wf1l   = (ushort*)alloc((size_t)128 * 128 * 2);
    ushort* wf2h   = (ushort*)alloc((size_t)128 * 128 * 2);
    ushort* wf2l   = (ushort*)alloc((size_t)128 * 128 * 2);
    ushort* wihfh  = (ushort*)alloc((size_t)512 * 128 * 2);
    ushort* wihfl  = (ushort*)alloc((size_t)512 * 128 * 2);
    ushort* whhfh  = (ushort*)alloc((size_t)512 * 128 * 2);
    ushort* whhfl  = (ushort*)alloc((size_t)512 * 128 * 2);
    float*  bcp    = (float*)alloc(512 * 4);

    // init
    hipMemsetAsync(c, 0, sz_feat, stream);
    hipMemsetAsync(hp0h, 0, sz_plane, stream);  // bf16 +0.0 == 0x0000
    hipMemsetAsync(hp0l, 0, sz_plane, stream);

    // CSR build: bucket binning -> per-node CSR
    bin_hist<<<dim3(NB, TT), 256, 0, stream>>>(ei, histG);
    scan_bins<<<TT, 256, 0, stream>>>(histG, bOffs);
    bin_scatter<<<dim3(NB, TT), 256, 0, stream>>>(ei, histG, binned);
    bucket_csr<<<dim3(NBUCK, TT), 256, 0, stream>>>(binned, bOffs, sorted, offs, dinv);

    // weight prep
    prep_w_gcn<<<32, 64, 0, stream>>>(W1, wf1h, wf1l);
    prep_w_gcn<<<32, 64, 0, stream>>>(W2, wf2h, wf2l);
    prep_w_lstm<<<128, 64, 0, stream>>>(Wih, wihfh, wihfl);
    prep_w_lstm<<<128, 64, 0, stream>>>(Whh, whhfh, whhfl);
    prep_bc<<<1, 512, 0, stream>>>(bih, bhh, bcp);

    const int gm64 = (NN + 63) / 64;  // 782
    const int gagg = (NN * 64) / 256; // 12500 blocks = 50000 waves

    for (int t = 0; t < TT; ++t) {
        const float* x = nf + (size_t)t * NN * FF;
        const float* dv = dinv + (size_t)t * NN;
        const int* of = offs + (size_t)t * (NN + 1);
        const int* so = sorted + (size_t)t * EE;

        // GCN layer 1 (fp32 A, LDS split)
        gemm_gcn_mfma<<<gm64, 256, 0, stream>>>(x, wf1h, wf1l, dv, hs, NN);
        aggregate_q<<<gagg, 256, 0, stream>>>(hs, of, so, dv, b1, xh, xl, NN);
        // GCN layer 2 (bf16 planes A, no LDS)
        gemm_frag<<<gm64, 256, 0, stream>>>(xh, xl, wf2h, wf2l, dv, hs, NN);
        aggregate_q<<<gagg, 256, 0, stream>>>(hs, of, so, dv, b2, xh, xl, NN);

        // fused LSTM step (h planes ping-pong)
        const ushort* hinh = (t & 1) ? hp1h : hp0h;
        const ushort* hinl = (t & 1) ? hp1l : hp0l;
        ushort* houth = (t & 1) ? hp0h : hp1h;
        ushort* houtl = (t & 1) ? hp0l : hp1l;
        lstm_frag<<<gm64, 512, 0, stream>>>(xh, xl, hinh, hinl, houth, houtl, h, c,
                                            wihfh, wihfl, whhfh, whhfl, bcp, NN);
    }
}

// Round 10
// 2560.224 us; speedup vs baseline: 4.9459x; 1.0587x over previous
//
#include <hip/hip_runtime.h>
#include <cstdint>
#include <cstddef>

// Problem constants (from reference)
#define NN 50000
#define TT 8
#define FF 128
#define HH 128
#define EE 800000

// binning geometry
#define NBUCK 782   // ceil(NN/64); bucket = dst >> 6
#define NB 128      // blocks per timestep in binning
#define CHUNK 6250  // EE / NB exactly

typedef __attribute__((ext_vector_type(8))) short bf16x8;
typedef __attribute__((ext_vector_type(4))) float f32x4;
typedef unsigned int uint;
typedef unsigned short ushort;

__device__ __forceinline__ float sigmoidf(float x) { return 1.0f / (1.0f + expf(-x)); }

__device__ __forceinline__ ushort f2bf_rne(float x) {
    uint u = __float_as_uint(x);
    uint r = (u + 0x7FFFu + ((u >> 16) & 1u)) >> 16;
    return (ushort)r;
}
__device__ __forceinline__ float bf2f(ushort b) { return __uint_as_float(((uint)b) << 16); }
__device__ __forceinline__ void split1(float x, ushort& hi, ushort& lo) {
    ushort h = f2bf_rne(x);
    hi = h;
    lo = f2bf_rne(x - bf2f(h));
}

// ---------------- bucket binning (all 8 timesteps) ----------------

// Phase A: per (t, edge-chunk) histogram over 782 buckets via LDS
__global__ __launch_bounds__(256) void bin_hist(const int* __restrict__ ei,
                                                int* __restrict__ histG) {
    __shared__ int hist[NBUCK];
    const int tid = threadIdx.x;
    const int blk = blockIdx.x, t = blockIdx.y;
    for (int i = tid; i < NBUCK; i += 256) hist[i] = 0;
    __syncthreads();
    const int* dst = ei + (size_t)t * 2 * EE + EE;
    const int base = blk * CHUNK;
    for (int i = tid; i < CHUNK; i += 256) atomicAdd(&hist[dst[base + i] >> 6], 1);
    __syncthreads();
    int* hg = histG + (size_t)t * NBUCK * NB;
    for (int i = tid; i < NBUCK; i += 256) hg[i * NB + blk] = hist[i];
}

// Phase B1: per-bucket totals — one wave per bucket (2 entries/lane + reduce)
__global__ __launch_bounds__(256) void bucket_tot(const int* __restrict__ histG,
                                                  int* __restrict__ btot) {
    const int t = blockIdx.y;
    const int wv = threadIdx.x >> 6;                 // 0..3
    const int lane = threadIdx.x & 63;
    const int buck = blockIdx.x * 4 + wv;
    if (buck >= NBUCK) return;
    const int* hg = histG + (size_t)t * NBUCK * NB + (size_t)buck * NB;
    int s = hg[lane] + hg[lane + 64];
#pragma unroll
    for (int m = 1; m < 64; m <<= 1) s += __shfl_xor(s, m);
    if (lane == 0) btot[t * NBUCK + buck] = s;
}

// Phase B2: exclusive scan of 782 bucket totals per t -> bOffs
__global__ __launch_bounds__(256) void scan_btot(const int* __restrict__ btot,
                                                 int* __restrict__ bOffs) {
    __shared__ int sums[256];
    const int t = blockIdx.x;
    const int* bt = btot + t * NBUCK;
    int* bo = bOffs + (size_t)t * (NBUCK + 1);
    const int tid = threadIdx.x;
    const int chunk = (NBUCK + 255) / 256;  // 4
    const int b = tid * chunk, e = min(b + chunk, NBUCK);
    int s = 0;
    for (int i = b; i < e; ++i) s += bt[i];
    sums[tid] = s;
    __syncthreads();
    for (int o = 1; o < 256; o <<= 1) {
        int v = 0;
        if (tid >= o) v = sums[tid - o];
        __syncthreads();
        if (tid >= o) sums[tid] += v;
        __syncthreads();
    }
    int pre = (tid == 0) ? 0 : sums[tid - 1];
    for (int i = b; i < e; ++i) { bo[i] = pre; pre += bt[i]; }
    if (tid == 255) bo[NBUCK] = EE;
}

// Phase B3: within-bucket prefix over the NB=128 block counts (wave scan),
// add bucket base, write back absolute cursor starts into histG
__global__ __launch_bounds__(256) void block_prefix(int* __restrict__ histG,
                                                    const int* __restrict__ bOffs) {
    const int t = blockIdx.y;
    const int wv = threadIdx.x >> 6;
    const int lane = threadIdx.x & 63;
    const int buck = blockIdx.x * 4 + wv;
    if (buck >= NBUCK) return;
    int* hg = histG + (size_t)t * NBUCK * NB + (size_t)buck * NB;
    const int base = bOffs[(size_t)t * (NBUCK + 1) + buck];
    const int a = hg[lane * 2], b = hg[lane * 2 + 1];
    int s = a + b;
#pragma unroll
    for (int o = 1; o < 64; o <<= 1) {
        const int v = __shfl_up(s, o);
        if (lane >= o) s += v;
    }
    const int excl = s - (a + b);  // exclusive prefix of this lane's pair
    hg[lane * 2]     = base + excl;
    hg[lane * 2 + 1] = base + excl + a;
}

// Phase C: scatter packed (dst&63)<<16 | src into bucket-grouped order
__global__ __launch_bounds__(256) void bin_scatter(const int* __restrict__ ei,
                                                   const int* __restrict__ histG,
                                                   uint* __restrict__ binned) {
    __shared__ int cur[NBUCK];
    const int tid = threadIdx.x;
    const int blk = blockIdx.x, t = blockIdx.y;
    const int* hg = histG + (size_t)t * NBUCK * NB;
    for (int i = tid; i < NBUCK; i += 256) cur[i] = hg[i * NB + blk];
    __syncthreads();
    const int* src = ei + (size_t)t * 2 * EE;
    const int* dst = src + EE;
    uint* bn = binned + (size_t)t * EE;
    const int base = blk * CHUNK;
    for (int i = tid; i < CHUNK; i += 256) {
        const int e = base + i;
        const int d = dst[e];
        const int s = src[e];
        const int pos = atomicAdd(&cur[d >> 6], 1);
        bn[pos] = ((uint)(d & 63) << 16) | (uint)s;
    }
}

// Phase D: bucket-grouped -> exact per-node CSR (offs, sorted, dinv)
__global__ __launch_bounds__(256) void bucket_csr(const uint* __restrict__ binned,
                                                  const int* __restrict__ bOffs,
                                                  int* __restrict__ sorted,
                                                  int* __restrict__ offs,
                                                  float* __restrict__ dinv) {
    __shared__ int cnt[64];
    __shared__ int base[64];
    const int tid = threadIdx.x;
    const int buck = blockIdx.x, t = blockIdx.y;
    if (tid < 64) cnt[tid] = 0;
    __syncthreads();
    const int* bo = bOffs + (size_t)t * (NBUCK + 1);
    const uint* bn = binned + (size_t)t * EE;
    const int e0 = bo[buck], e1 = bo[buck + 1];
    for (int e = e0 + tid; e < e1; e += 256) atomicAdd(&cnt[bn[e] >> 16], 1);
    __syncthreads();
    if (tid == 0) {
        int pre = e0;
#pragma unroll
        for (int i = 0; i < 64; ++i) { base[i] = pre; pre += cnt[i]; }
    }
    __syncthreads();
    if (tid < 64) {
        const int d = buck * 64 + tid;
        if (d < NN) {
            offs[(size_t)t * (NN + 1) + d] = base[tid];
            dinv[(size_t)t * NN + d] = rsqrtf((float)(cnt[tid] + 1));
        }
        cnt[tid] = 0;  // reuse as cursor
    }
    __syncthreads();
    int* so = sorted + (size_t)t * EE;
    for (int e = e0 + tid; e < e1; e += 256) {
        const uint p = bn[e];
        const int dl = p >> 16;
        const int pos = base[dl] + atomicAdd(&cnt[dl], 1);
        so[pos] = (int)(p & 0xFFFF);
    }
    if (buck == 0 && tid == 0) offs[(size_t)t * (NN + 1) + NN] = EE;
}

// ---------------- weight prep ----------------
__global__ void prep_w_gcn(const float* __restrict__ W, ushort* __restrict__ oh,
                           ushort* __restrict__ ol) {
    const int bx = blockIdx.x;           // kc5*8 + q, 32 blocks
    const int kc5 = bx >> 3, q = bx & 7;
    const int l = threadIdx.x;           // 64
    const int n = q * 16 + (l & 15);
    const int kb = kc5 * 32 + (l >> 4) * 8;
    const size_t o = ((size_t)bx * 64 + l) * 8;
#pragma unroll
    for (int j = 0; j < 8; ++j) {
        float v = W[(size_t)(kb + j) * 128 + n];
        split1(v, oh[o + j], ol[o + j]);
    }
}

__global__ void prep_w_lstm(const float* __restrict__ W, ushort* __restrict__ oh,
                            ushort* __restrict__ ol) {
    const int bx = blockIdx.x;           // kc5*32 + q, 128 blocks
    const int kc5 = bx >> 5, q = bx & 31;
    const int l = threadIdx.x;           // 64
    const int c15 = l & 15;
    const int g = q & 3, kk = q >> 2;
    const int srow = g * 128 + kk * 16 + c15;
    const int kb = kc5 * 32 + (l >> 4) * 8;
    const size_t o = ((size_t)bx * 64 + l) * 8;
#pragma unroll
    for (int j = 0; j < 8; ++j) {
        float v = W[(size_t)srow * 128 + kb + j];
        split1(v, oh[o + j], ol[o + j]);
    }
}

__global__ void prep_bc(const float* __restrict__ bih, const float* __restrict__ bhh,
                        float* __restrict__ bcp) {
    const int cp = threadIdx.x;  // 512
    const int c15 = cp & 15, q = cp >> 4;
    const int g = q & 3, kk = q >> 2;
    const int srow = g * 128 + kk * 16 + c15;
    bcp[cp] = bih[srow] + bhh[srow];
}

// ---------------- GCN GEMM layer 1 (fp32 A via LDS split): hs = (A@W)*dinv ----------------
__global__ __launch_bounds__(256) void gemm_gcn_mfma(const float* __restrict__ A,
                                                     const ushort* __restrict__ Wfh,
                                                     const ushort* __restrict__ Wfl,
                                                     const float* __restrict__ dinv,
                                                     float* __restrict__ C, int M) {
    __shared__ ushort Ah[64][40];
    __shared__ ushort Al[64][40];
    const int tid = threadIdx.x;
    const int lane = tid & 63;
    const int w = tid >> 6;
    const int wm = w >> 1, wn = w & 1;
    const int l15 = lane & 15, l4 = lane >> 4;
    const int m0 = blockIdx.x * 64;

    f32x4 acc[2][4];
#pragma unroll
    for (int i = 0; i < 2; ++i)
#pragma unroll
        for (int j = 0; j < 4; ++j) acc[i][j] = (f32x4){0.f, 0.f, 0.f, 0.f};

    const int srow = tid >> 2;
    const int sseg = tid & 3;
    const bool aval = (m0 + srow) < M;
    const float* aptr = A + (size_t)(m0 + srow) * 128 + sseg * 8;

    for (int kc5 = 0; kc5 < 4; ++kc5) {
        float4 v0 = {0.f, 0.f, 0.f, 0.f}, v1 = {0.f, 0.f, 0.f, 0.f};
        if (aval) {
            v0 = *(const float4*)(aptr + kc5 * 32);
            v1 = *(const float4*)(aptr + kc5 * 32 + 4);
        }
        union { uint4 u; ushort s[8]; } ph, pl;
        split1(v0.x, ph.s[0], pl.s[0]); split1(v0.y, ph.s[1], pl.s[1]);
        split1(v0.z, ph.s[2], pl.s[2]); split1(v0.w, ph.s[3], pl.s[3]);
        split1(v1.x, ph.s[4], pl.s[4]); split1(v1.y, ph.s[5], pl.s[5]);
        split1(v1.z, ph.s[6], pl.s[6]); split1(v1.w, ph.s[7], pl.s[7]);
        *(uint4*)&Ah[srow][sseg * 8] = ph.u;
        *(uint4*)&Al[srow][sseg * 8] = pl.u;
        __syncthreads();

        bf16x8 bh[4], bl[4];
#pragma unroll
        for (int nf = 0; nf < 4; ++nf) {
            const size_t o = ((size_t)(kc5 * 8 + wn * 4 + nf) * 64 + lane) * 8;
            bh[nf] = *(const bf16x8*)(Wfh + o);
            bl[nf] = *(const bf16x8*)(Wfl + o);
        }
        bf16x8 ahf[2], alf[2];
#pragma unroll
        for (int mf = 0; mf < 2; ++mf) {
            ahf[mf] = *(const bf16x8*)&Ah[wm * 32 + mf * 16 + l15][l4 * 8];
            alf[mf] = *(const bf16x8*)&Al[wm * 32 + mf * 16 + l15][l4 * 8];
        }
#pragma unroll
        for (int mf = 0; mf < 2; ++mf)
#pragma unroll
            for (int nf = 0; nf < 4; ++nf) {
                acc[mf][nf] = __builtin_amdgcn_mfma_f32_16x16x32_bf16(ahf[mf], bh[nf], acc[mf][nf], 0, 0, 0);
                acc[mf][nf] = __builtin_amdgcn_mfma_f32_16x16x32_bf16(ahf[mf], bl[nf], acc[mf][nf], 0, 0, 0);
                acc[mf][nf] = __builtin_amdgcn_mfma_f32_16x16x32_bf16(alf[mf], bh[nf], acc[mf][nf], 0, 0, 0);
            }
        __syncthreads();
    }

#pragma unroll
    for (int mf = 0; mf < 2; ++mf)
#pragma unroll
        for (int r = 0; r < 4; ++r) {
            const int row = m0 + wm * 32 + mf * 16 + l4 * 4 + r;
            if (row < M) {
                const float d = dinv[row];
                float* cp = C + (size_t)row * 128 + wn * 64 + l15;
#pragma unroll
                for (int nf = 0; nf < 4; ++nf) cp[nf * 16] = acc[mf][nf][r] * d;
            }
        }
}

// ---------------- GCN GEMM layer 2 (A from bf16 hi/lo planes, no LDS/barriers) ----------------
__global__ __launch_bounds__(256) void gemm_frag(const ushort* __restrict__ Xh,
                                                 const ushort* __restrict__ Xl,
                                                 const ushort* __restrict__ Wfh,
                                                 const ushort* __restrict__ Wfl,
                                                 const float* __restrict__ dinv,
                                                 float* __restrict__ C, int M) {
    const int tid = threadIdx.x;
    const int lane = tid & 63;
    const int w = tid >> 6;
    const int wm = w >> 1, wn = w & 1;
    const int l15 = lane & 15, l4 = lane >> 4;
    const int m0 = blockIdx.x * 64;

    f32x4 acc[2][4];
#pragma unroll
    for (int i = 0; i < 2; ++i)
#pragma unroll
        for (int j = 0; j < 4; ++j) acc[i][j] = (f32x4){0.f, 0.f, 0.f, 0.f};

    size_t abase[2];
#pragma unroll
    for (int mf = 0; mf < 2; ++mf)
        abase[mf] = (size_t)(m0 + wm * 32 + mf * 16 + l15) * 128 + l4 * 8;

#pragma unroll
    for (int kc5 = 0; kc5 < 4; ++kc5) {
        bf16x8 ahf[2], alf[2];
#pragma unroll
        for (int mf = 0; mf < 2; ++mf) {
            ahf[mf] = *(const bf16x8*)(Xh + abase[mf] + kc5 * 32);
            alf[mf] = *(const bf16x8*)(Xl + abase[mf] + kc5 * 32);
        }
#pragma unroll
        for (int nf = 0; nf < 4; ++nf) {
            const size_t o = ((size_t)(kc5 * 8 + wn * 4 + nf) * 64 + lane) * 8;
            const bf16x8 bh = *(const bf16x8*)(Wfh + o);
            const bf16x8 bl = *(const bf16x8*)(Wfl + o);
#pragma unroll
            for (int mf = 0; mf < 2; ++mf) {
                acc[mf][nf] = __builtin_amdgcn_mfma_f32_16x16x32_bf16(ahf[mf], bh, acc[mf][nf], 0, 0, 0);
                acc[mf][nf] = __builtin_amdgcn_mfma_f32_16x16x32_bf16(ahf[mf], bl, acc[mf][nf], 0, 0, 0);
                acc[mf][nf] = __builtin_amdgcn_mfma_f32_16x16x32_bf16(alf[mf], bh, acc[mf][nf], 0, 0, 0);
            }
        }
    }

#pragma unroll
    for (int mf = 0; mf < 2; ++mf)
#pragma unroll
        for (int r = 0; r < 4; ++r) {
            const int row = m0 + wm * 32 + mf * 16 + l4 * 4 + r;
            if (row < M) {
                const float d = dinv[row];
                float* cp = C + (size_t)row * 128 + wn * 64 + l15;
#pragma unroll
                for (int nf = 0; nf < 4; ++nf) cp[nf * 16] = acc[mf][nf][r] * d;
            }
        }
}

// ---------------- aggregate: wave per node, quarter-wave per edge, 8 edges in flight ----------------
__global__ __launch_bounds__(256) void aggregate_q(const float* __restrict__ hs,
                                                   const int* __restrict__ offs,
                                                   const int* __restrict__ sorted,
                                                   const float* __restrict__ dinv,
                                                   const float* __restrict__ bias,
                                                   ushort* __restrict__ outh,
                                                   ushort* __restrict__ outl, int n) {
    const int lane = threadIdx.x & 63;
    const int qt = lane >> 4, li = lane & 15;
    const int wave = (blockIdx.x * blockDim.x + threadIdx.x) >> 6;
    const int nwaves = (gridDim.x * blockDim.x) >> 6;
    for (int d = wave; d < n; d += nwaves) {
        const int e0 = offs[d], e1 = offs[d + 1];
        float4 a0 = {0, 0, 0, 0}, b0 = {0, 0, 0, 0};
        float4 a1 = {0, 0, 0, 0}, b1 = {0, 0, 0, 0};
        const int fb = li * 8;
        for (int e = e0; e < e1; e += 8) {
            const int sl = ((lane < 8) && (e + lane < e1)) ? sorted[e + lane] : 0;
            const int s0 = __shfl(sl, qt);
            const int s1 = __shfl(sl, qt + 4);
            if (e + qt < e1) {
                const float4 v0 = *(const float4*)&hs[(size_t)s0 * 128 + fb];
                const float4 v1 = *(const float4*)&hs[(size_t)s0 * 128 + fb + 4];
                a0.x += v0.x; a0.y += v0.y; a0.z += v0.z; a0.w += v0.w;
                b0.x += v1.x; b0.y += v1.y; b0.z += v1.z; b0.w += v1.w;
            }
            if (e + qt + 4 < e1) {
                const float4 v0 = *(const float4*)&hs[(size_t)s1 * 128 + fb];
                const float4 v1 = *(const float4*)&hs[(size_t)s1 * 128 + fb + 4];
                a1.x += v0.x; a1.y += v0.y; a1.z += v0.z; a1.w += v0.w;
                b1.x += v1.x; b1.y += v1.y; b1.z += v1.z; b1.w += v1.w;
            }
        }
        a0.x += a1.x; a0.y += a1.y; a0.z += a1.z; a0.w += a1.w;
        b0.x += b1.x; b0.y += b1.y; b0.z += b1.z; b0.w += b1.w;
        // cross-quarter reduce (lanes differing in bits 4,5)
#pragma unroll
        for (int m = 16; m <= 32; m <<= 1) {
            a0.x += __shfl_xor(a0.x, m); a0.y += __shfl_xor(a0.y, m);
            a0.z += __shfl_xor(a0.z, m); a0.w += __shfl_xor(a0.w, m);
            b0.x += __shfl_xor(b0.x, m); b0.y += __shfl_xor(b0.y, m);
            b0.z += __shfl_xor(b0.z, m); b0.w += __shfl_xor(b0.w, m);
        }

        const float di = dinv[d];
        const float4 s0 = *(const float4*)&hs[(size_t)d * 128 + fb];
        const float4 s1 = *(const float4*)&hs[(size_t)d * 128 + fb + 4];
        const float4 c0 = *(const float4*)&bias[fb];
        const float4 c1 = *(const float4*)&bias[fb + 4];
        float o[8];
        o[0] = fmaxf(di * (a0.x + s0.x) + c0.x, 0.f);
        o[1] = fmaxf(di * (a0.y + s0.y) + c0.y, 0.f);
        o[2] = fmaxf(di * (a0.z + s0.z) + c0.z, 0.f);
        o[3] = fmaxf(di * (a0.w + s0.w) + c0.w, 0.f);
        o[4] = fmaxf(di * (b0.x + s1.x) + c1.x, 0.f);
        o[5] = fmaxf(di * (b0.y + s1.y) + c1.y, 0.f);
        o[6] = fmaxf(di * (b0.z + s1.z) + c1.z, 0.f);
        o[7] = fmaxf(di * (b0.w + s1.w) + c1.w, 0.f);
        ushort hh[8], ll[8];
#pragma unroll
        for (int j = 0; j < 8; ++j) split1(o[j], hh[j], ll[j]);
        if (qt == 0) {
            ushort4 p0 = {hh[0], hh[1], hh[2], hh[3]};
            ushort4 p1 = {hh[4], hh[5], hh[6], hh[7]};
            *(ushort4*)&outh[(size_t)d * 128 + fb] = p0;
            *(ushort4*)&outh[(size_t)d * 128 + fb + 4] = p1;
        } else if (qt == 1) {
            ushort4 p0 = {ll[0], ll[1], ll[2], ll[3]};
            ushort4 p1 = {ll[4], ll[5], ll[6], ll[7]};
            *(ushort4*)&outl[(size_t)d * 128 + fb] = p0;
            *(ushort4*)&outl[(size_t)d * 128 + fb + 4] = p1;
        }
    }
}

// ---------------- fused LSTM step (frag A loads, no LDS, no barriers) ----------------
__global__ __launch_bounds__(512) void lstm_frag(const ushort* __restrict__ Xh,
                                                 const ushort* __restrict__ Xl,
                                                 const ushort* __restrict__ Hinh,
                                                 const ushort* __restrict__ Hinl,
                                                 ushort* __restrict__ Houth,
                                                 ushort* __restrict__ Houtl,
                                                 float* __restrict__ hout,
                                                 float* __restrict__ c,
                                                 const ushort* __restrict__ Wihfh,
                                                 const ushort* __restrict__ Wihfl,
                                                 const ushort* __restrict__ Whhfh,
                                                 const ushort* __restrict__ Whhfl,
                                                 const float* __restrict__ bcp, int M) {
    const int tid = threadIdx.x;
    const int lane = tid & 63;
    const int w = tid >> 6;          // 0..7
    const int wm = w >> 2, wn = w & 3;
    const int l15 = lane & 15, l4 = lane >> 4;
    const int m0 = blockIdx.x * 64;

    f32x4 acc[2][8];
#pragma unroll
    for (int i = 0; i < 2; ++i)
#pragma unroll
        for (int j = 0; j < 8; ++j) acc[i][j] = (f32x4){0.f, 0.f, 0.f, 0.f};

    size_t abase[2];
#pragma unroll
    for (int mf = 0; mf < 2; ++mf)
        abase[mf] = (size_t)(m0 + wm * 32 + mf * 16 + l15) * 128 + l4 * 8;

#pragma unroll
    for (int halfK = 0; halfK < 2; ++halfK) {
        const ushort* Ah = halfK ? Hinh : Xh;
        const ushort* Al = halfK ? Hinl : Xl;
        const ushort* Bfh = halfK ? Whhfh : Wihfh;
        const ushort* Bfl = halfK ? Whhfl : Wihfl;
#pragma unroll
        for (int kc5 = 0; kc5 < 4; ++kc5) {
            bf16x8 ahf[2], alf[2];
#pragma unroll
            for (int mf = 0; mf < 2; ++mf) {
                ahf[mf] = *(const bf16x8*)(Ah + abase[mf] + kc5 * 32);
                alf[mf] = *(const bf16x8*)(Al + abase[mf] + kc5 * 32);
            }
#pragma unroll
            for (int nf = 0; nf < 8; ++nf) {
                const size_t o = ((size_t)(kc5 * 32 + wn * 8 + nf) * 64 + lane) * 8;
                const bf16x8 bh = *(const bf16x8*)(Bfh + o);
                const bf16x8 bl = *(const bf16x8*)(Bfl + o);
#pragma unroll
                for (int mf = 0; mf < 2; ++mf) {
                    acc[mf][nf] = __builtin_amdgcn_mfma_f32_16x16x32_bf16(ahf[mf], bh, acc[mf][nf], 0, 0, 0);
                    acc[mf][nf] = __builtin_amdgcn_mfma_f32_16x16x32_bf16(ahf[mf], bl, acc[mf][nf], 0, 0, 0);
                    acc[mf][nf] = __builtin_amdgcn_mfma_f32_16x16x32_bf16(alf[mf], bh, acc[mf][nf], 0, 0, 0);
                }
            }
        }
    }

    float bb[8];
#pragma unroll
    for (int nf = 0; nf < 8; ++nf) bb[nf] = bcp[l15 + 16 * (wn * 8 + nf)];
#pragma unroll
    for (int mf = 0; mf < 2; ++mf)
#pragma unroll
        for (int r = 0; r < 4; ++r) {
            const int row = m0 + wm * 32 + mf * 16 + l4 * 4 + r;
            if (row >= M) continue;
#pragma unroll
            for (int kl = 0; kl < 2; ++kl) {
                const float gi = acc[mf][kl * 4 + 0][r] + bb[kl * 4 + 0];
                const float gf = acc[mf][kl * 4 + 1][r] + bb[kl * 4 + 1];
                const float gg = acc[mf][kl * 4 + 2][r] + bb[kl * 4 + 2];
                const float go = acc[mf][kl * 4 + 3][r] + bb[kl * 4 + 3];
                const int k = (2 * wn + kl) * 16 + l15;
                const size_t idx = (size_t)row * 128 + k;
                const float cn = sigmoidf(gf) * c[idx] + sigmoidf(gi) * tanhf(gg);
                const float hn = sigmoidf(go) * tanhf(cn);
                c[idx] = cn;
                hout[idx] = hn;
                ushort hh, hl;
                split1(hn, hh, hl);
                Houth[idx] = hh;
                Houtl[idx] = hl;
            }
        }
}

// ---------------- launch ----------------
extern "C" void kernel_launch(void* const* d_in, const int* in_sizes, int n_in,
                              void* d_out, int out_size, void* d_ws, size_t ws_size,
                              hipStream_t stream) {
    const float* nf  = (const float*)d_in[0];  // [T,N,F]
    const int*   ei  = (const int*)d_in[1];    // [T,2,E]
    const float* W1  = (const float*)d_in[2];
    const float* b1  = (const float*)d_in[3];
    const float* W2  = (const float*)d_in[4];
    const float* b2  = (const float*)d_in[5];
    const float* Wih = (const float*)d_in[6];  // [512,128]
    const float* Whh = (const float*)d_in[7];
    const float* bih = (const float*)d_in[8];
    const float* bhh = (const float*)d_in[9];
    float* h = (float*)d_out;  // [N,128] fp32 hidden (final answer)

    const size_t AL = 256;
    auto rnd = [&](size_t b) { return (b + AL - 1) & ~(AL - 1); };
    const size_t sz_feat  = (size_t)NN * 128 * 4;   // fp32 plane
    const size_t sz_plane = (size_t)NN * 128 * 2;   // bf16 plane
    const size_t need = rnd(sz_feat) * 2                       // hs, c
                      + rnd(sz_plane) * 6                      // xh,xl + h ping-pong hi/lo
                      + rnd((size_t)TT * EE * 4) * 2           // binned, sorted
                      + rnd((size_t)TT * NBUCK * NB * 4)       // histG
                      + rnd((size_t)TT * NBUCK * 4)            // btot
                      + rnd((size_t)TT * (NBUCK + 1) * 4)      // bOffs
                      + rnd((size_t)TT * (NN + 1) * 4)         // offs
                      + rnd((size_t)TT * NN * 4)               // dinv
                      + rnd((size_t)128 * 128 * 2) * 4
                      + rnd((size_t)512 * 128 * 2) * 4
                      + rnd(512 * 4);
    if (ws_size < need) return;  // fail visibly (incorrect), not fatally

    char* ws = (char*)d_ws;
    size_t off = 0;
    auto alloc = [&](size_t bytes) -> void* {
        void* p = ws + off;
        off += rnd(bytes);
        return p;
    };
    float*  hs     = (float*)alloc(sz_feat);
    float*  c      = (float*)alloc(sz_feat);
    ushort* xh     = (ushort*)alloc(sz_plane);
    ushort* xl     = (ushort*)alloc(sz_plane);
    ushort* hp0h   = (ushort*)alloc(sz_plane);
    ushort* hp0l   = (ushort*)alloc(sz_plane);
    ushort* hp1h   = (ushort*)alloc(sz_plane);
    ushort* hp1l   = (ushort*)alloc(sz_plane);
    uint*   binned = (uint*)alloc((size_t)TT * EE * 4);
    int*    sorted = (int*)alloc((size_t)TT * EE * 4);
    int*    histG  = (int*)alloc((size_t)TT * NBUCK * NB * 4);
    int*    btot   = (int*)alloc((size_t)TT * NBUCK * 4);
    int*    bOffs  = (int*)alloc((size_t)TT * (NBUCK + 1) * 4);
    int*    offs   = (int*)alloc((size_t)TT * (NN + 1) * 4);
    float*  dinv   = (float*)alloc((size_t)TT * NN * 4);
    ushort* wf1h   = (ushort*)alloc((size_t)128 * 128 * 2);
    ushort* wf1l   = (ushort*)alloc((size_t)128 * 128 * 2);
    ushort* wf2h   = (ushort*)alloc((size_t)128 * 128 * 2);
    ushort* wf2l   = (ushort*)alloc((size_t)128 * 128 * 2);
    ushort* wihfh  = (ushort*)alloc((size_t)512 * 128 * 2);
    ushort* wihfl  = (ushort*)alloc((size_t)512 * 128 * 2);
    ushort* whhfh  = (ushort*)alloc((size_t)512 * 128 * 2);
    ushort* whhfl  = (ushort*)alloc((size_t)512 * 128 * 2);
    float*  bcp    = (float*)alloc(512 * 4);

    // init
    hipMemsetAsync(c, 0, sz_feat, stream);
    hipMemsetAsync(hp0h, 0, sz_plane, stream);  // bf16 +0.0 == 0x0000
    hipMemsetAsync(hp0l, 0, sz_plane, stream);

    // CSR build: bucket binning (hierarchical scan) -> per-node CSR
    const int gb4 = (NBUCK + 3) / 4;  // 196
    bin_hist<<<dim3(NB, TT), 256, 0, stream>>>(ei, histG);
    bucket_tot<<<dim3(gb4, TT), 256, 0, stream>>>(histG, btot);
    scan_btot<<<TT, 256, 0, stream>>>(btot, bOffs);
    block_prefix<<<dim3(gb4, TT), 256, 0, stream>>>(histG, bOffs);
    bin_scatter<<<dim3(NB, TT), 256, 0, stream>>>(ei, histG, binned);
    bucket_csr<<<dim3(NBUCK, TT), 256, 0, stream>>>(binned, bOffs, sorted, offs, dinv);

    // weight prep
    prep_w_gcn<<<32, 64, 0, stream>>>(W1, wf1h, wf1l);
    prep_w_gcn<<<32, 64, 0, stream>>>(W2, wf2h, wf2l);
    prep_w_lstm<<<128, 64, 0, stream>>>(Wih, wihfh, wihfl);
    prep_w_lstm<<<128, 64, 0, stream>>>(Whh, whhfh, whhfl);
    prep_bc<<<1, 512, 0, stream>>>(bih, bhh, bcp);

    const int gm64 = (NN + 63) / 64;  // 782
    const int gagg = (NN * 64) / 256; // 12500 blocks = 50000 waves

    for (int t = 0; t < TT; ++t) {
        const float* x = nf + (size_t)t * NN * FF;
        const float* dv = dinv + (size_t)t * NN;
        const int* of = offs + (size_t)t * (NN + 1);
        const int* so = sorted + (size_t)t * EE;

        // GCN layer 1 (fp32 A, LDS split)
        gemm_gcn_mfma<<<gm64, 256, 0, stream>>>(x, wf1h, wf1l, dv, hs, NN);
        aggregate_q<<<gagg, 256, 0, stream>>>(hs, of, so, dv, b1, xh, xl, NN);
        // GCN layer 2 (bf16 planes A, no LDS)
        gemm_frag<<<gm64, 256, 0, stream>>>(xh, xl, wf2h, wf2l, dv, hs, NN);
        aggregate_q<<<gagg, 256, 0, stream>>>(hs, of, so, dv, b2, xh, xl, NN);

        // fused LSTM step (h planes ping-pong)
        const ushort* hinh = (t & 1) ? hp1h : hp0h;
        const ushort* hinl = (t & 1) ? hp1l : hp0l;
        ushort* houth = (t & 1) ? hp0h : hp1h;
        ushort* houtl = (t & 1) ? hp0l : hp1l;
        lstm_frag<<<gm64, 512, 0, stream>>>(xh, xl, hinh, hinl, houth, houtl, h, c,
                                            wihfh, wihfl, whhfh, whhfl, bcp, NN);
    }
}